// Round 8
// baseline (19.194 us; speedup 1.0000x reference)
//
#include <hip/hip_runtime.h>

// out[b,o] = min_i max(x[b,i], w[i,o])   (forward of STE expr == hard min)
// B=512, I=512, O=1024, fp32, values uniform in [0,1).
//
// Split design:
//  K1 sort_rows: counting-sort x[b,:] by 256 value buckets (one 512-thr block
//     per row) -> keys[b*512+pos] = {w-row byte offset, x valbits}, bucket-
//     ascending. ~1.5 us.
//  K2 scan: pure gather scan, NO LDS, NO barriers. One wave per (row b,
//     128-o slice): entries 0..127 live in 4 VGPRs/lane (one dwordx4 from
//     keys), broadcast by compile-time v_readlane; w loads are dwordx2
//     (2 o's per lane). First 64 entries straight-line (full load ILP), then
//     per-8 early-exit tail (exit bound = next entry's bucket lower bound:
//     all unseen values >= floor(val*256)/256 >= A  => exact), then a
//     ~never-executed uniform-load fallback for 128+.

#define B_DIM 512
#define I_DIM 512
#define O_DIM 1024
#define NBUCK 256

#define RL(v_, l_) ((unsigned)__builtin_amdgcn_readlane((int)(v_), (l_)))
#define RFL(v_) ((unsigned)__builtin_amdgcn_readfirstlane((int)(v_)))

typedef float float2v __attribute__((ext_vector_type(2)));

// ---------------- kernel 1: per-row counting sort ----------------
__global__ __launch_bounds__(512) void sort_rows(
    const float* __restrict__ x, uint2* __restrict__ keys) {
  __shared__ unsigned int hist[NBUCK];
  __shared__ unsigned int wssum[4];
  const int t = threadIdx.x;
  const int b = blockIdx.x;
  const int lane = t & 63;

  const float xval = x[b * I_DIM + t];
  int bb = (int)(xval * 256.0f);
  bb = bb > 255 ? 255 : (bb < 0 ? 0 : bb);
  if (t < NBUCK) hist[t] = 0;
  __syncthreads();
  atomicAdd(&hist[bb], 1u);
  __syncthreads();

  unsigned v = 0, cnt = 0;
  if (t < NBUCK) {
    cnt = hist[t];
    v = cnt;
#pragma unroll
    for (int d = 1; d < 64; d <<= 1) {
      const unsigned n = __shfl_up(v, d, 64);
      if (lane >= d) v += n;
    }
    if (lane == 63) wssum[t >> 6] = v;
  }
  __syncthreads();
  if (t < NBUCK) {
    unsigned add = 0;
#pragma unroll
    for (int ww = 0; ww < 4; ++ww)
      if (ww < (t >> 6)) add += wssum[ww];
    hist[t] = v + add - cnt;   // exclusive bucket base
  }
  __syncthreads();
  const unsigned pos = atomicAdd(&hist[bb], 1u);
  keys[b * I_DIM + pos] =
      make_uint2((unsigned)t * (unsigned)(O_DIM * 4), __float_as_uint(xval));
}

// ---------------- kernel 2: barrier-free early-exit scan ----------------
__global__ __launch_bounds__(256, 4) void scan_rows(
    const uint2* __restrict__ keys, const float* __restrict__ w,
    float* __restrict__ out) {
  const int b = blockIdx.x;
  const int sl = blockIdx.y * 4 + (threadIdx.x >> 6);  // o-slice 0..7
  const int lane = threadIdx.x & 63;
  const uint2* kb = keys + b * I_DIM;
  const char* wb = reinterpret_cast<const char*>(w);
  const unsigned o8 = (unsigned)(sl * 128 + lane * 2) * 4u;  // byte offset in row

  // entries 0..127: lane l holds entries 2l (q.x=off,q.y=val), 2l+1 (q.z,q.w)
  const uint4 q = *reinterpret_cast<const uint4*>(kb + 2 * lane);

  float A0 = 3.402823466e+38f, A1 = A0;

  // straight-line first 64 entries: no checks, full global-load ILP
#pragma unroll
  for (int c = 0; c < 8; ++c) {
    float2v wv[8];
    float xv[8];
#pragma unroll
    for (int e = 0; e < 8; ++e) {
      const int g = c * 8 + e;
      const unsigned off = RL((g & 1) ? q.z : q.x, g >> 1);
      const unsigned xb  = RL((g & 1) ? q.w : q.y, g >> 1);
      xv[e] = __uint_as_float(xb);
      wv[e] = *reinterpret_cast<const float2v*>(wb + (off + o8));
    }
#pragma unroll
    for (int e = 0; e < 8; ++e) {
      A0 = fminf(A0, fmaxf(xv[e], wv[e].x));
      A1 = fminf(A1, fmaxf(xv[e], wv[e].y));
    }
  }

  int k = 64;
  // register-resident adaptive tail: entries 64..127, exit check per 8
#pragma unroll
  for (int c = 8; c < 16; ++c) {
    const float nx = __uint_as_float(RL(q.y, 4 * c));          // value of entry 8c
    const float th = (float)(int)(nx * 256.0f) * 0.00390625f;  // bucket lower bound
    if (!__any(A0 > th || A1 > th)) break;                     // exact early exit
#pragma unroll
    for (int e = 0; e < 8; ++e) {
      const int g = c * 8 + e;
      const unsigned off = RL((g & 1) ? q.z : q.x, g >> 1);
      const unsigned xb  = RL((g & 1) ? q.w : q.y, g >> 1);
      const float2v wvv = *reinterpret_cast<const float2v*>(wb + (off + o8));
      A0 = fminf(A0, fmaxf(__uint_as_float(xb), wvv.x));
      A1 = fminf(A1, fmaxf(__uint_as_float(xb), wvv.y));
    }
    k += 8;
  }

  // fallback: entries 128..511 (probability ~0; correctness only)
  if (k >= 128) {
    while (k < I_DIM) {
      const uint2 e0 = kb[k];
      const float nx = __uint_as_float(RFL(e0.y));
      const float th = (float)(int)(nx * 256.0f) * 0.00390625f;
      if (!__any(A0 > th || A1 > th)) break;
#pragma unroll
      for (int u = 0; u < 8; ++u) {
        const uint2 e = kb[k + u];
        const unsigned off = RFL(e.x);
        const unsigned xb = RFL(e.y);
        const float2v wvv = *reinterpret_cast<const float2v*>(wb + (off + o8));
        A0 = fminf(A0, fmaxf(__uint_as_float(xb), wvv.x));
        A1 = fminf(A1, fmaxf(__uint_as_float(xb), wvv.y));
      }
      k += 8;
    }
  }

  float2v r;
  r.x = A0;
  r.y = A1;
  *reinterpret_cast<float2v*>(&out[b * O_DIM + sl * 128 + lane * 2]) = r;
}

// ---------------- tiny fallback if ws too small (never expected) ----------------
__global__ __launch_bounds__(256) void brute_simple(
    const float* __restrict__ x, const float* __restrict__ w,
    float* __restrict__ out) {
  const int o = blockIdx.y * 256 + threadIdx.x;
  const int b = blockIdx.x;
  float A = 3.402823466e+38f;
  for (int i = 0; i < I_DIM; ++i)
    A = fminf(A, fmaxf(x[b * I_DIM + i], w[i * O_DIM + o]));
  out[b * O_DIM + o] = A;
}

extern "C" void kernel_launch(void* const* d_in, const int* in_sizes, int n_in,
                              void* d_out, int out_size, void* d_ws, size_t ws_size,
                              hipStream_t stream) {
  const float* x = (const float*)d_in[0];   // [512, 512]
  const float* w = (const float*)d_in[1];   // [512, 1024]
  float* out = (float*)d_out;               // [512, 1024]

  const size_t keys_bytes = (size_t)B_DIM * I_DIM * sizeof(uint2);  // 2 MB
  if (ws_size >= keys_bytes) {
    uint2* keys = (uint2*)d_ws;
    sort_rows<<<B_DIM, 512, 0, stream>>>(x, keys);
    dim3 grid(B_DIM, 2);                      // 1024 blocks x 4 waves
    scan_rows<<<grid, 256, 0, stream>>>(keys, w, out);
  } else {
    dim3 grid(B_DIM, O_DIM / 256);
    brute_simple<<<grid, 256, 0, stream>>>(x, w, out);
  }
}